// Round 1
// 394.639 us; speedup vs baseline: 1.0420x; 1.0420x over previous
//
#include <hip/hip_runtime.h>
#include <math.h>

typedef unsigned long long u64;
typedef unsigned int u32;
typedef _Float16 h8v __attribute__((ext_vector_type(8)));  // 8 fp16 (4 VGPRs)
typedef float    f4v __attribute__((ext_vector_type(4)));  // MFMA acc
typedef float    f2v __attribute__((ext_vector_type(2)));  // v_pk_*_f32 pair

#define MFMA16(a,b,c) __builtin_amdgcn_mfma_f32_16x16x32_f16(a, b, c, 0, 0, 0)

#define B_ 4
#define N_ 8192
#define K_ 16
#define W0_ 64
#define W1_ 128
#define W2_ 256
#define X0_ 96   // padded K-dim layer-1 inputs (64 feat + 3 coord + 29 zero)
#define X1_ 160  // padded K-dim layer-2 inputs (128 feat + 3 coord + 29 zero)
#define QAD_ 32  // knn MFMA operand row width (14 used dims + 18 zero)
#define CAP_ 128 // per-query knn candidate-list capacity (mean ~36, +10 sigma)

// ---------------- merged prep: points + weight conversions + part zeroing ----------------
__global__ __launch_bounds__(256) void prep_kernel(
    const float* __restrict__ x,
    const float* __restrict__ stem_w, const float* __restrict__ stem_b,
    const float* __restrict__ hmix_a, const float* __restrict__ hmix_b,
    const float* __restrict__ hmix_c,
    float* __restrict__ coords4, _Float16* __restrict__ fx0,
    _Float16* __restrict__ fx1,
    const float* __restrict__ b1_w, const float* __restrict__ b2_w,
    const float* __restrict__ h1w,
    _Float16* __restrict__ w1m, _Float16* __restrict__ w1d,
    _Float16* __restrict__ w2m, _Float16* __restrict__ w2d,
    _Float16* __restrict__ h1wT,
    _Float16* __restrict__ qa, _Float16* __restrict__ cbq,
    float* __restrict__ part) {
  const int bi = blockIdx.x;
  const int tid = threadIdx.x;
  const int PB = (B_*N_)/4;          // 8192
  if (bi < PB) {
    const int p = bi * 4 + (tid >> 6);
    const int o = tid & 63;
    const float x0 = x[p*4+0], x1 = x[p*4+1], x2 = x[p*4+2], x3 = x[p*4+3];
    const float z = hmix_a[0]*x2 + hmix_b[0]*x3 + hmix_c[0];
    float acc = stem_b[o] + x0*stem_w[0*W0_+o] + x1*stem_w[1*W0_+o]
              + x2*stem_w[2*W0_+o] + x3*stem_w[3*W0_+o];
    fx0[p*X0_+o] = (_Float16)fmaxf(acc, 0.f);
    if (o < 32) {   // tail: 3 coords + 29 zeros (both layers' inputs)
      const float tv = (o==0) ? x0 : (o==1) ? x1 : (o==2) ? z : 0.f;
      fx0[p*X0_+W0_+o] = (_Float16)tv;
      fx1[(size_t)p*X1_+W1_+o] = (_Float16)tv;
    }
    if (o == 0) {
      const float xx = x0*x0 + x1*x1 + z*z;
      ((float4*)coords4)[p] = make_float4(x0, x1, z, xx);
    } else if (o == 1) {
      // knn A-operand row: [hi3, lo3, hi3, lo3, 1, 1, 0...] (hi/lo fp16 split)
      const _Float16 hx = (_Float16)x0, hy = (_Float16)x1, hz = (_Float16)z;
      const _Float16 lx = (_Float16)(x0 - (float)hx);
      const _Float16 ly = (_Float16)(x1 - (float)hy);
      const _Float16 lz = (_Float16)(z  - (float)hz);
      const _Float16 one = (_Float16)1.f, Z = (_Float16)0.f;
      h8v a0 = {hx, hy, hz, lx, ly, lz, hx, hy};
      h8v a1 = {hz, lx, ly, lz, one, one, Z, Z};
      h8v zr = {Z,Z,Z,Z,Z,Z,Z,Z};
      *(h8v*)(qa + (size_t)p*QAD_)      = a0;
      *(h8v*)(qa + (size_t)p*QAD_ + 8)  = a1;
      *(h8v*)(qa + (size_t)p*QAD_ + 16) = zr;
      *(h8v*)(qa + (size_t)p*QAD_ + 24) = zr;
    } else if (o == 2) {
      // knn B-operand row: [-2hi3, -2lo3, -2lo3, -2hi3, xxhi, xxlo, 0...]
      // dot(A_i, B_j) = -2 (hi_i+lo_i).(hi_j+lo_j) + xx_j  (products exact in fp32 acc)
      const _Float16 hx = (_Float16)x0, hy = (_Float16)x1, hz = (_Float16)z;
      const _Float16 lx = (_Float16)(x0 - (float)hx);
      const _Float16 ly = (_Float16)(x1 - (float)hy);
      const _Float16 lz = (_Float16)(z  - (float)hz);
      const float xx = x0*x0 + x1*x1 + z*z;
      const _Float16 xh = (_Float16)xx;
      const _Float16 xl = (_Float16)(xx - (float)xh);
      const _Float16 nhx = (_Float16)(-2.f*(float)hx);
      const _Float16 nhy = (_Float16)(-2.f*(float)hy);
      const _Float16 nhz = (_Float16)(-2.f*(float)hz);
      const _Float16 nlx = (_Float16)(-2.f*(float)lx);
      const _Float16 nly = (_Float16)(-2.f*(float)ly);
      const _Float16 nlz = (_Float16)(-2.f*(float)lz);
      const _Float16 Z = (_Float16)0.f;
      h8v b0 = {nhx, nhy, nhz, nlx, nly, nlz, nlx, nly};
      h8v b1 = {nlz, nhx, nhy, nhz, xh, xl, Z, Z};
      h8v zr = {Z,Z,Z,Z,Z,Z,Z,Z};
      *(h8v*)(cbq + (size_t)p*QAD_)      = b0;
      *(h8v*)(cbq + (size_t)p*QAD_ + 8)  = b1;
      *(h8v*)(cbq + (size_t)p*QAD_ + 16) = zr;
      *(h8v*)(cbq + (size_t)p*QAD_ + 24) = zr;
    }
  } else if (bi < PB + W1_) {        // wconv layer1
    const int o = bi - PB, c = tid;
    if (c < X0_) {
      float mv = 0.f, dv = 0.f;
      if (c < W0_)        { const float wm = b1_w[(W0_+c)*W1_+o]; mv = wm; dv = b1_w[c*W1_+o] - wm; }
      else if (c < W0_+3) { const float wp = b1_w[(2*W0_+(c-W0_))*W1_+o]; mv = wp; dv = -wp; }
      w1m[o*X0_+c] = (_Float16)mv;
      w1d[o*X0_+c] = (_Float16)dv;
    }
  } else if (bi < PB + W1_ + W2_) {  // wconv layer2
    const int o = bi - PB - W1_, c = tid;
    if (c < X1_) {
      float mv = 0.f, dv = 0.f;
      if (c < W1_)        { const float wm = b2_w[(W1_+c)*W2_+o]; mv = wm; dv = b2_w[c*W2_+o] - wm; }
      else if (c < W1_+3) { const float wp = b2_w[(2*W1_+(c-W1_))*W2_+o]; mv = wp; dv = -wp; }
      w2m[o*X1_+c] = (_Float16)mv;
      w2d[o*X1_+c] = (_Float16)dv;
    }
  } else if (bi < PB + W1_ + 2*W2_) { // head1 transpose
    const int o = bi - PB - W1_ - W2_;
    for (int c = tid; c < 512; c += 256)
      h1wT[(size_t)o*512 + c] = (_Float16)h1w[(size_t)c*256 + o];
  } else {                            // zero part (B_*W2_ = 1024 floats)
    ((float4*)part)[tid] = make_float4(0.f, 0.f, 0.f, 0.f);
  }
}

// ---------------- knn v2: MFMA distance tiles + threshold filter + DPP extraction ----------
// R18: distance matrix is matmul-shaped; move -2ci.cj + xxj onto the matrix pipe via
// hi/lo fp16 split (products exact in fp32 accumulate, total err ~1e-6 << ~1e-3 gaps).
// Pass A (proven fp32 packed scan + sixteenth_of_minima, half sample) gives a valid
// per-query upper bound Th on the 16th distance (subset order-stat argument, r9).
// Phase 1: each wave MFMA-scans a quarter of candidates for all 16 queries; entries
// with D < Th - xx_i + margin go to per-query LDS lists (mean ~36, CAP 128 ~ +10 sigma).
// Phase 2: 16-round wave-min extraction (proven DPP chain) with index tie-break.
#define DPP_MIN(v, ctrl)                                                        \
  { const int _t = __builtin_amdgcn_update_dpp(0, __float_as_int(v),            \
      ctrl, 0xF, 0xF, false);                                                   \
    v = fminf(v, __int_as_float(_t)); }

__device__ __forceinline__ float sixteenth_of_minima(float v) {
  float th = 0.f;
#pragma unroll
  for (int r = 0; r < 16; ++r) {
    float w = v;
    DPP_MIN(w, 0x111); DPP_MIN(w, 0x112); DPP_MIN(w, 0x114); DPP_MIN(w, 0x118);
    DPP_MIN(w, 0x142); DPP_MIN(w, 0x143);   // row_bcast15 / row_bcast31
    const float mv = __int_as_float(
        __builtin_amdgcn_readlane(__float_as_int(w), 63));
    th = mv;
    v = (v == mv) ? INFINITY : v;
  }
  return th;
}

#define KNN_DIST2(dA, dB)                                                       \
  const f2v cjx = {cj.x, cj.x}, cjy = {cj.y, cj.y},                             \
            cjz = {cj.z, cj.z}, cjw = {cj.w, cj.w};                             \
  f2v tA = cAx * cjx;                                                           \
  tA = __builtin_elementwise_fma(cAy, cjy, tA);                                 \
  tA = __builtin_elementwise_fma(cAz, cjz, tA);                                 \
  const f2v dA = __builtin_elementwise_fma(tA, m2, cAw + cjw);                  \
  f2v tB = cBx * cjx;                                                           \
  tB = __builtin_elementwise_fma(cBy, cjy, tB);                                 \
  tB = __builtin_elementwise_fma(cBz, cjz, tB);                                 \
  const f2v dB = __builtin_elementwise_fma(tB, m2, cBw + cjw);

__global__ __launch_bounds__(256, 4) void knn_kernel(
    const float* __restrict__ coords4, const _Float16* __restrict__ qa,
    const _Float16* __restrict__ cbq, int* __restrict__ knn_idx) {
  const int tid = threadIdx.x;
  const int wid = tid >> 6;
  const int lane = tid & 63;
  const int col = lane & 15, quad = lane >> 4;
  const int p0 = blockIdx.x * 16;    // block of 16 never straddles batch
  const int bb = (p0 >> 13) << 13;

  __shared__ float s_Tp[16];
  __shared__ int   s_cnt[16];
  __shared__ float s_ld[16][CAP_];
  __shared__ int   s_li[16][CAP_];
  if (tid < 16) s_cnt[tid] = 0;

  // ---- pass A: fp32 packed scan of half sample -> per-query threshold bound
  const float4* cb = ((const float4*)coords4) + bb;
  const int q0 = p0 + wid * 4;
  const float4 c0 = ((const float4*)coords4)[q0+0];
  const float4 c1 = ((const float4*)coords4)[q0+1];
  const float4 c2 = ((const float4*)coords4)[q0+2];
  const float4 c3 = ((const float4*)coords4)[q0+3];
  const f2v m2 = {-2.f, -2.f};
  const f2v cAx = {c0.x, c1.x}, cAy = {c0.y, c1.y}, cAz = {c0.z, c1.z}, cAw = {c0.w, c1.w};
  const f2v cBx = {c2.x, c3.x}, cBy = {c2.y, c3.y}, cBz = {c2.z, c3.z}, cBw = {c2.w, c3.w};

  float lm0 = INFINITY, lm1 = INFINITY, lm2 = INFINITY, lm3 = INFINITY;
  for (int it = 0; it < 64; ++it) {
    const float4 cj = cb[it*64 + lane];
    KNN_DIST2(dA, dB)
    lm0 = fminf(lm0, fmaxf(dA[0], 0.f));
    lm1 = fminf(lm1, fmaxf(dA[1], 0.f));
    lm2 = fminf(lm2, fmaxf(dB[0], 0.f));
    lm3 = fminf(lm3, fmaxf(dB[1], 0.f));
  }
  const float Th0 = sixteenth_of_minima(lm0);
  const float Th1 = sixteenth_of_minima(lm1);
  const float Th2 = sixteenth_of_minima(lm2);
  const float Th3 = sixteenth_of_minima(lm3);
  if (lane == 0) {
    // margin covers fp32-vs-MFMA rounding (abs + tail-magnitude term)
    s_Tp[wid*4+0] = Th0 - c0.w + (1e-3f + 1e-5f*c0.w);
    s_Tp[wid*4+1] = Th1 - c1.w + (1e-3f + 1e-5f*c1.w);
    s_Tp[wid*4+2] = Th2 - c2.w + (1e-3f + 1e-5f*c2.w);
    s_Tp[wid*4+3] = Th3 - c3.w + (1e-3f + 1e-5f*c3.w);
  }
  __syncthreads();

  // ---- phase 1: MFMA scan; D[query=quad*4+r][cand=tile+col] = -2ci.cj + xxj
  const float Tq0 = s_Tp[quad*4+0], Tq1 = s_Tp[quad*4+1],
              Tq2 = s_Tp[quad*4+2], Tq3 = s_Tp[quad*4+3];
  const h8v afrag = *(const h8v*)(qa + (size_t)(p0 + col)*QAD_ + quad*8);
  const int cb0 = wid * 2048;                 // this wave's candidate quarter
  const _Float16* cbp = cbq + (size_t)(bb + cb0 + col)*QAD_ + quad*8;

  h8v bcur = *(const h8v*)cbp;
#pragma unroll 2
  for (int t = 0; t < 128; ++t) {
    const int nx = ((t < 127) ? (t+1) : 0) * 16 * QAD_;
    const h8v bnxt = *(const h8v*)(cbp + nx);
    f4v acc = {0.f, 0.f, 0.f, 0.f};
    acc = MFMA16(afrag, bcur, acc);
    const int cidx = cb0 + t*16 + col;
    if (acc[0] < Tq0) { const int pos = atomicAdd(&s_cnt[quad*4+0], 1);
      if (pos < CAP_) { s_ld[quad*4+0][pos] = acc[0]; s_li[quad*4+0][pos] = cidx; } }
    if (acc[1] < Tq1) { const int pos = atomicAdd(&s_cnt[quad*4+1], 1);
      if (pos < CAP_) { s_ld[quad*4+1][pos] = acc[1]; s_li[quad*4+1][pos] = cidx; } }
    if (acc[2] < Tq2) { const int pos = atomicAdd(&s_cnt[quad*4+2], 1);
      if (pos < CAP_) { s_ld[quad*4+2][pos] = acc[2]; s_li[quad*4+2][pos] = cidx; } }
    if (acc[3] < Tq3) { const int pos = atomicAdd(&s_cnt[quad*4+3], 1);
      if (pos < CAP_) { s_ld[quad*4+3][pos] = acc[3]; s_li[quad*4+3][pos] = cidx; } }
    bcur = bnxt;
  }
  __syncthreads();

  // ---- phase 2: per query (4 per wave), extract 16 smallest (idx tie-break)
  for (int qq = 0; qq < 4; ++qq) {
    const int q = wid*4 + qq;
    const int cnt = s_cnt[q];
    const int L = (cnt < CAP_) ? cnt : CAP_;
    float d0 = (lane      < L) ? s_ld[q][lane]      : INFINITY;
    float d1 = (lane + 64 < L) ? s_ld[q][lane + 64] : INFINITY;
    int   i0 = (lane      < L) ? s_li[q][lane]      : 0x7fffffff;
    int   i1 = (lane + 64 < L) ? s_li[q][lane + 64] : 0x7fffffff;
    int keep = 0;
    for (int r = 0; r < K_; ++r) {
      float dl = d0; int il = i0; bool s1 = false;
      if (d1 < dl || (d1 == dl && i1 < il)) { dl = d1; il = i1; s1 = true; }
      float w = dl;
      DPP_MIN(w, 0x111); DPP_MIN(w, 0x112); DPP_MIN(w, 0x114); DPP_MIN(w, 0x118);
      DPP_MIN(w, 0x142); DPP_MIN(w, 0x143);
      const float dmin = __int_as_float(
          __builtin_amdgcn_readlane(__float_as_int(w), 63));
      u64 m = __ballot(dl == dmin);
      int bi = 0x7fffffff, bl = 0;
      do {
        const int s = (int)__ffsll((unsigned long long)m) - 1; m &= m - 1;
        const int ii = __builtin_amdgcn_readlane(il, s);
        if (ii < bi) { bi = ii; bl = s; }
      } while (m);
      if (lane == bl) { if (s1) d1 = INFINITY; else d0 = INFINITY; }
      if (lane == r) keep = bi;
    }
    if (lane < K_) knn_idx[(size_t)(p0 + q)*K_ + lane] = keep;
  }
}

// ---------------- MFMA local_agg: transposed layout + 4-slot LDS dbuf + fused gmax ----------------
// r17: FOUR k-slots staged per buffer -> 4 stages, 5 barriers total (was 9).
template<int KS, int NPASS, bool GMAX>
__global__ __launch_bounds__(256) void aggm_kernel(
    const _Float16* __restrict__ fx, const int* __restrict__ knn_idx,
    const _Float16* __restrict__ midT, const _Float16* __restrict__ difT,
    const float* __restrict__ bw,
    _Float16* __restrict__ fo, const int ostr, u32* __restrict__ part) {
  const int XD  = KS*32;
  const int XDP = XD + 8;               // +16B pad per row
  const int CH  = KS*4;                 // uint4 chunks per row
  const int p0 = blockIdx.x * 16;
  const int bb = (p0 >> 13) << 13;
  const int tid = threadIdx.x;
  const int w = tid >> 6, lane = tid & 63, col = lane & 15, quad = lane >> 4;
  const int koff = quad * 8;

  __shared__ int s_idx[256];            // [point m][k]
  __shared__ _Float16 sA[2][64*(KS*32+8)];   // 2 bufs x 4 k-slots x 16 rows

  s_idx[tid] = knn_idx[p0*K_ + tid];

  // ---- C part (k-independent): A = own 16 point rows, B = difT ----
  f4v cacc[NPASS][2];
  {
    h8v Ao[KS];
    const _Float16* ap = fx + (size_t)(p0+col)*XD + koff;
#pragma unroll
    for (int kk = 0; kk < KS; ++kk) Ao[kk] = *(const h8v*)(ap + kk*32);
#pragma unroll
    for (int ps = 0; ps < NPASS; ++ps) {
      const int o0 = ps*128 + w*32;
      const _Float16* b0 = difT + (size_t)(o0 + col)*XD + koff;
      const _Float16* b1 = difT + (size_t)(o0 + 16 + col)*XD + koff;
      f4v c0 = {0.f,0.f,0.f,0.f}, c1 = {0.f,0.f,0.f,0.f};
#pragma unroll
      for (int kk = 0; kk < KS; ++kk) {
        c0 = MFMA16(Ao[kk], *(const h8v*)(b0 + kk*32), c0);
        c1 = MFMA16(Ao[kk], *(const h8v*)(b1 + kk*32), c1);
      }
      cacc[ps][0] = c0; cacc[ps][1] = c1;
    }
  }

  // ---- B fragments for ALL passes in registers ----
  h8v Bf[NPASS][2][KS];
  float bias[NPASS][2];
#pragma unroll
  for (int ps = 0; ps < NPASS; ++ps) {
    const int o0 = ps*128 + w*32;
#pragma unroll
    for (int kk = 0; kk < KS; ++kk) {
      Bf[ps][0][kk] = *(const h8v*)(midT + (size_t)(o0 + col)*XD + kk*32 + koff);
      Bf[ps][1][kk] = *(const h8v*)(midT + (size_t)(o0 + 16 + col)*XD + kk*32 + koff);
    }
    bias[ps][0] = bw[o0 + col];
    bias[ps][1] = bw[o0 + 16 + col];
  }
  __syncthreads();   // s_idx ready

  // ---- stage slots {0..3} ----  (sA row r: point r&15, slot base + (r>>4))
  for (int c = tid; c < 64*CH; c += 256) {
    const int r = c / CH, o = c - r*CH;
    *(uint4*)&sA[0][r*XDP + o*8] =
        *(const uint4*)(fx + (size_t)(bb + s_idx[((r&15)<<4) + (r>>4)])*XD + o*8);
  }
  __syncthreads();

  f4v M[NPASS][2];
#pragma unroll
  for (int ps = 0; ps < NPASS; ++ps) {
    M[ps][0] = (f4v){-INFINITY,-INFINITY,-INFINITY,-INFINITY};
    M[ps][1] = (f4v){-INFINITY,-INFINITY,-INFINITY,-INFINITY};
  }

  for (int s = 0; s < 4; ++s) {
    const int buf = s & 1;
    if (s < 3) {   // stage slots {4s+4 .. 4s+7} into the other buffer
      for (int c = tid; c < 64*CH; c += 256) {
        const int r = c / CH, o = c - r*CH;
        *(uint4*)&sA[buf^1][r*XDP + o*8] =
            *(const uint4*)(fx + (size_t)(bb + s_idx[((r&15)<<4) + 4*s+4 + (r>>4)])*XD + o*8);
      }
    }
#pragma unroll
    for (int half = 0; half < 4; ++half) {
      h8v Ac[KS];
      const _Float16* ap = &sA[buf][(half*16 + col)*XDP + koff];
#pragma unroll
      for (int kk = 0; kk < KS; ++kk) Ac[kk] = *(const h8v*)(ap + kk*32);
#pragma unroll
      for (int ps = 0; ps < NPASS; ++ps) {
        f4v d0 = {0.f,0.f,0.f,0.f}, d1 = {0.f,0.f,0.f,0.f};
#pragma unroll
        for (int kk = 0; kk < KS; ++kk) {
          d0 = MFMA16(Ac[kk], Bf[ps][0][kk], d0);
          d1 = MFMA16(Ac[kk], Bf[ps][1][kk], d1);
        }
#pragma unroll
        for (int e = 0; e < 4; ++e) {
          M[ps][0][e] = fmaxf(M[ps][0][e], d0[e]);
          M[ps][1][e] = fmaxf(M[ps][1][e], d1[e]);
        }
      }
    }
    if (s < 3) __syncthreads();   // staged visible; readers done before overwrite
  }

  // ---- epilogue: out[p][o] = max(M + C + bias, 0); lane holds rows quad*4+reg ----
  const int prow = p0 + (quad << 2);
  const int bq = p0 >> 13;
#pragma unroll
  for (int ps = 0; ps < NPASS; ++ps) {
    const int o0 = ps*128 + w*32;
    const int oa = o0 + col, ob = oa + 16;
    float v0[4], v1[4];
#pragma unroll
    for (int reg = 0; reg < 4; ++reg) {
      v0[reg] = fmaxf(M[ps][0][reg] + cacc[ps][0][reg] + bias[ps][0], 0.f);
      v1[reg] = fmaxf(M[ps][1][reg] + cacc[ps][1][reg] + bias[ps][1], 0.f);
      fo[(size_t)(prow+reg)*ostr + oa] = (_Float16)v0[reg];
      fo[(size_t)(prow+reg)*ostr + ob] = (_Float16)v1[reg];
    }
    if (GMAX) {   // block-local max over 16 points, then one atomic per output
      float bm0 = fmaxf(fmaxf(v0[0], v0[1]), fmaxf(v0[2], v0[3]));
      float bm1 = fmaxf(fmaxf(v1[0], v1[1]), fmaxf(v1[2], v1[3]));
      bm0 = fmaxf(bm0, __shfl_xor(bm0, 16, 64));
      bm0 = fmaxf(bm0, __shfl_xor(bm0, 32, 64));
      bm1 = fmaxf(bm1, __shfl_xor(bm1, 16, 64));
      bm1 = fmaxf(bm1, __shfl_xor(bm1, 32, 64));
      if (quad == 0) {
        atomicMax(part + bq*W2_ + oa, __float_as_uint(bm0));
        atomicMax(part + bq*W2_ + ob, __float_as_uint(bm1));
      }
    }
  }
}

// ---------------- glob FC from fused-max part -> g2h fp16 ----------------
__global__ __launch_bounds__(256) void gfc_kernel(
    const float* __restrict__ part, const float* __restrict__ gw,
    const float* __restrict__ gb, _Float16* __restrict__ g2h) {
  const int b = blockIdx.x;
  const int o = threadIdx.x;
  __shared__ float s_g[W2_];
  s_g[o] = part[b*W2_ + o];   // bits from atomicMax(u32) == float bits (>=0)
  __syncthreads();
  float acc = gb[o];
  for (int d = 0; d < W2_; ++d) acc += s_g[d]*gw[d*W2_ + o];
  g2h[b*W2_ + o] = (_Float16)fmaxf(acc, 0.f);
}

// ---------------- head: 32 points/block MFMA GEMM + tiny second layer ----------------
__global__ __launch_bounds__(256) void headm_kernel(
    const _Float16* __restrict__ f2h, const _Float16* __restrict__ g2h,
    const _Float16* __restrict__ h1wT, const float* __restrict__ h1b,
    const float* __restrict__ h2w, const float* __restrict__ h2b,
    const float* __restrict__ x,
    const float* __restrict__ thresh, const float* __restrict__ sharp,
    const float* __restrict__ scale,
    float* __restrict__ out) {
  const int p0 = blockIdx.x * 32;
  const int b = p0 >> 13;
  const int tid = threadIdx.x;
  const int w = tid >> 6, lane = tid & 63, col = lane & 15, quad = lane >> 4;

  __shared__ _Float16 sA[32*520];   // 32 points x 512 (padded to 520)
  __shared__ float    sh[32*260];   // relu(h1) f32

  for (int t = tid; t < 32*32; t += 256) {       // f2h part (16B chunks)
    const int r = t >> 5, cc = (t & 31) * 8;
    *(uint4*)&sA[r*520 + cc] = *(const uint4*)&f2h[(size_t)(p0+r)*W2_ + cc];
  }
  for (int t = tid; t < 32*32; t += 256) {       // g2h broadcast part
    const int r = t >> 5, cc = (t & 31) * 8;
    *(uint4*)&sA[r*520 + 256 + cc] = *(const uint4*)&g2h[b*W2_ + cc];
  }
  __syncthreads();

  f4v acc[2][4];
#pragma unroll
  for (int r = 0; r < 2; ++r)
#pragma unroll
    for (int t = 0; t < 4; ++t) acc[r][t] = (f4v){0.f,0.f,0.f,0.f};

  for (int kk = 0; kk < 16; ++kk) {
    const h8v a0 = *(const h8v*)&sA[col*520 + kk*32 + quad*8];
    const h8v a1 = *(const h8v*)&sA[(16+col)*520 + kk*32 + quad*8];
#pragma unroll
    for (int t = 0; t < 4; ++t) {
      const h8v bt = *(const h8v*)&h1wT[(size_t)(w*64 + t*16 + col)*512 + kk*32 + quad*8];
      acc[0][t] = MFMA16(a0, bt, acc[0][t]);
      acc[1][t] = MFMA16(a1, bt, acc[1][t]);
    }
  }
#pragma unroll
  for (int r = 0; r < 2; ++r)
#pragma unroll
    for (int t = 0; t < 4; ++t) {
      const int o = w*64 + t*16 + col;
      const float bv = h1b[o];
#pragma unroll
      for (int reg = 0; reg < 4; ++reg)
        sh[(r*16 + quad*4 + reg)*260 + o] = fmaxf(acc[r][t][reg] + bv, 0.f);
    }
  __syncthreads();

  if (tid < 96) {
    const int pp = tid / 3, c = tid % 3;
    float s = h2b[c];
    for (int d = 0; d < 256; ++d) s += sh[pp*260 + d] * h2w[d*3 + c];
    if (c == 0) {
      const float hag = x[(size_t)(p0+pp)*4 + 3];
      s += scale[0] / (1.f + expf(-sharp[0]*(thresh[0] - hag)));
    }
    out[(size_t)(p0+pp)*3 + c] = s;
  }
}

// ---------------- launch ----------------
extern "C" void kernel_launch(void* const* d_in, const int* in_sizes, int n_in,
                              void* d_out, int out_size, void* d_ws, size_t ws_size,
                              hipStream_t stream) {
  const float* x       = (const float*)d_in[0];
  const float* hmix_a  = (const float*)d_in[1];
  const float* hmix_b  = (const float*)d_in[2];
  const float* hmix_c  = (const float*)d_in[3];
  const float* stem_w  = (const float*)d_in[4];
  const float* stem_b  = (const float*)d_in[5];
  const float* b1_w    = (const float*)d_in[6];
  const float* b1_b    = (const float*)d_in[7];
  const float* b2_w    = (const float*)d_in[8];
  const float* b2_b    = (const float*)d_in[9];
  const float* glob_w  = (const float*)d_in[10];
  const float* glob_b  = (const float*)d_in[11];
  const float* head1_w = (const float*)d_in[12];
  const float* head1_b = (const float*)d_in[13];
  const float* head2_w = (const float*)d_in[14];
  const float* head2_b = (const float*)d_in[15];
  const float* thresh  = (const float*)d_in[16];
  const float* sharp   = (const float*)d_in[17];
  const float* scale   = (const float*)d_in[18];
  float* out = (float*)d_out;

  char* base = (char*)d_ws;
  float*     coords4 = (float*)    (base + 0);          // 512 KB
  int*       idxb    = (int*)      (base + 524288);     // 2 MB
  _Float16*  fx0     = (_Float16*) (base + 2621440);    // 6 MB   (32768*96*2)
  _Float16*  fx1     = (_Float16*) (base + 8912896);    // 10 MB  (32768*160*2)
  _Float16*  f2h     = (_Float16*) (base + 19398656);   // 16 MB  (32768*256*2)
  // qa/cbq alias the f2h region: consumed by knn, f2h written only later (aggm2)
  _Float16*  qa      = (_Float16*) (base + 19398656);   // 2 MB   (32768*32*2)
  _Float16*  cbq     = (_Float16*) (base + 21495808);   // 2 MB
  _Float16*  w1m     = (_Float16*) (base + 36175872);   // 24 KB  (128*96*2)
  _Float16*  w1d     = (_Float16*) (base + 36200448);   // 24 KB
  _Float16*  w2m     = (_Float16*) (base + 36225024);   // 80 KB  (256*160*2)
  _Float16*  w2d     = (_Float16*) (base + 36306944);   // 80 KB
  _Float16*  h1wT    = (_Float16*) (base + 36388864);   // 256 KB (256*512*2)
  float*     part    = (float*)    (base + 36651008);   // 4 KB (4*256 f32, fused max)
  _Float16*  g2h     = (_Float16*) (base + 36782080);   // 2 KB
  const int NP = B_ * N_;   // 32768 points

  prep_kernel<<<NP/4 + W1_ + 2*W2_ + 1, 256, 0, stream>>>(
      x, stem_w, stem_b, hmix_a, hmix_b, hmix_c, coords4, fx0, fx1,
      b1_w, b2_w, head1_w, w1m, w1d, w2m, w2d, h1wT, qa, cbq, part);
  knn_kernel<<<NP/16, 256, 0, stream>>>(coords4, qa, cbq, idxb);
  aggm_kernel<3, 1, false><<<NP/16, 256, 0, stream>>>(
      fx0, idxb, w1m, w1d, b1_b, fx1, X1_, (u32*)0);
  aggm_kernel<5, 2, true><<<NP/16, 256, 0, stream>>>(
      fx1, idxb, w2m, w2d, b2_b, f2h, W2_, (u32*)part);
  gfc_kernel<<<B_, 256, 0, stream>>>(part, glob_w, glob_b, g2h);
  headm_kernel<<<NP/32, 256, 0, stream>>>(f2h, g2h, h1wT, head1_b, head2_w, head2_b,
                                          x, thresh, sharp, scale, out);
}

// Round 2
// 375.542 us; speedup vs baseline: 1.0950x; 1.0509x over previous
//
#include <hip/hip_runtime.h>
#include <math.h>

typedef unsigned long long u64;
typedef unsigned int u32;
typedef _Float16 h8v __attribute__((ext_vector_type(8)));  // 8 fp16 (4 VGPRs)
typedef float    f4v __attribute__((ext_vector_type(4)));  // MFMA acc (16x16)
typedef float    f16v __attribute__((ext_vector_type(16))); // MFMA acc (32x32)
typedef float    f2v __attribute__((ext_vector_type(2)));  // v_pk_*_f32 pair

#define MFMA16(a,b,c) __builtin_amdgcn_mfma_f32_16x16x32_f16(a, b, c, 0, 0, 0)
#define MFMA32(a,b,c) __builtin_amdgcn_mfma_f32_32x32x16_f16(a, b, c, 0, 0, 0)

#define B_ 4
#define N_ 8192
#define K_ 16
#define W0_ 64
#define W1_ 128
#define W2_ 256
#define X0_ 96   // padded K-dim layer-1 inputs (64 feat + 3 coord + 29 zero)
#define X1_ 160  // padded K-dim layer-2 inputs (128 feat + 3 coord + 29 zero)
#define QAD_ 16  // knn MFMA operand row width (14 used dims + 2 zero, K=16)
#define CAP_ 128 // per-query knn candidate-list capacity (mean ~36, +10 sigma)

// ---------------- merged prep: points + weight conversions + part zeroing ----------------
__global__ __launch_bounds__(256) void prep_kernel(
    const float* __restrict__ x,
    const float* __restrict__ stem_w, const float* __restrict__ stem_b,
    const float* __restrict__ hmix_a, const float* __restrict__ hmix_b,
    const float* __restrict__ hmix_c,
    float* __restrict__ coords4, _Float16* __restrict__ fx0,
    _Float16* __restrict__ fx1,
    const float* __restrict__ b1_w, const float* __restrict__ b2_w,
    const float* __restrict__ h1w,
    _Float16* __restrict__ w1m, _Float16* __restrict__ w1d,
    _Float16* __restrict__ w2m, _Float16* __restrict__ w2d,
    _Float16* __restrict__ h1wT,
    _Float16* __restrict__ qa, _Float16* __restrict__ cbq,
    float* __restrict__ part) {
  const int bi = blockIdx.x;
  const int tid = threadIdx.x;
  const int PB = (B_*N_)/4;          // 8192
  if (bi < PB) {
    const int p = bi * 4 + (tid >> 6);
    const int o = tid & 63;
    const float x0 = x[p*4+0], x1 = x[p*4+1], x2 = x[p*4+2], x3 = x[p*4+3];
    const float z = hmix_a[0]*x2 + hmix_b[0]*x3 + hmix_c[0];
    float acc = stem_b[o] + x0*stem_w[0*W0_+o] + x1*stem_w[1*W0_+o]
              + x2*stem_w[2*W0_+o] + x3*stem_w[3*W0_+o];
    fx0[p*X0_+o] = (_Float16)fmaxf(acc, 0.f);
    if (o < 32) {   // tail: 3 coords + 29 zeros (both layers' inputs)
      const float tv = (o==0) ? x0 : (o==1) ? x1 : (o==2) ? z : 0.f;
      fx0[p*X0_+W0_+o] = (_Float16)tv;
      fx1[(size_t)p*X1_+W1_+o] = (_Float16)tv;
    }
    if (o == 0) {
      const float xx = x0*x0 + x1*x1 + z*z;
      ((float4*)coords4)[p] = make_float4(x0, x1, z, xx);
    } else if (o == 1) {
      // knn A-operand row (K=16): [hi3, lo3, hi3, lo3, 1, 1, 0, 0] (hi/lo fp16 split)
      const _Float16 hx = (_Float16)x0, hy = (_Float16)x1, hz = (_Float16)z;
      const _Float16 lx = (_Float16)(x0 - (float)hx);
      const _Float16 ly = (_Float16)(x1 - (float)hy);
      const _Float16 lz = (_Float16)(z  - (float)hz);
      const _Float16 one = (_Float16)1.f, Z = (_Float16)0.f;
      h8v a0 = {hx, hy, hz, lx, ly, lz, hx, hy};
      h8v a1 = {hz, lx, ly, lz, one, one, Z, Z};
      *(h8v*)(qa + (size_t)p*QAD_)      = a0;
      *(h8v*)(qa + (size_t)p*QAD_ + 8)  = a1;
    } else if (o == 2) {
      // knn B-operand row (K=16): [-2hi3, -2lo3, -2lo3, -2hi3, xxhi, xxlo, 0, 0]
      // dot(A_i, B_j) = -2 (hi_i+lo_i).(hi_j+lo_j) + xx_j  (products exact in fp32 acc)
      const _Float16 hx = (_Float16)x0, hy = (_Float16)x1, hz = (_Float16)z;
      const _Float16 lx = (_Float16)(x0 - (float)hx);
      const _Float16 ly = (_Float16)(x1 - (float)hy);
      const _Float16 lz = (_Float16)(z  - (float)hz);
      const float xx = x0*x0 + x1*x1 + z*z;
      const _Float16 xh = (_Float16)xx;
      const _Float16 xl = (_Float16)(xx - (float)xh);
      const _Float16 nhx = (_Float16)(-2.f*(float)hx);
      const _Float16 nhy = (_Float16)(-2.f*(float)hy);
      const _Float16 nhz = (_Float16)(-2.f*(float)hz);
      const _Float16 nlx = (_Float16)(-2.f*(float)lx);
      const _Float16 nly = (_Float16)(-2.f*(float)ly);
      const _Float16 nlz = (_Float16)(-2.f*(float)lz);
      const _Float16 Z = (_Float16)0.f;
      h8v b0 = {nhx, nhy, nhz, nlx, nly, nlz, nlx, nly};
      h8v b1 = {nlz, nhx, nhy, nhz, xh, xl, Z, Z};
      *(h8v*)(cbq + (size_t)p*QAD_)      = b0;
      *(h8v*)(cbq + (size_t)p*QAD_ + 8)  = b1;
    }
  } else if (bi < PB + W1_) {        // wconv layer1
    const int o = bi - PB, c = tid;
    if (c < X0_) {
      float mv = 0.f, dv = 0.f;
      if (c < W0_)        { const float wm = b1_w[(W0_+c)*W1_+o]; mv = wm; dv = b1_w[c*W1_+o] - wm; }
      else if (c < W0_+3) { const float wp = b1_w[(2*W0_+(c-W0_))*W1_+o]; mv = wp; dv = -wp; }
      w1m[o*X0_+c] = (_Float16)mv;
      w1d[o*X0_+c] = (_Float16)dv;
    }
  } else if (bi < PB + W1_ + W2_) {  // wconv layer2
    const int o = bi - PB - W1_, c = tid;
    if (c < X1_) {
      float mv = 0.f, dv = 0.f;
      if (c < W1_)        { const float wm = b2_w[(W1_+c)*W2_+o]; mv = wm; dv = b2_w[c*W2_+o] - wm; }
      else if (c < W1_+3) { const float wp = b2_w[(2*W1_+(c-W1_))*W2_+o]; mv = wp; dv = -wp; }
      w2m[o*X1_+c] = (_Float16)mv;
      w2d[o*X1_+c] = (_Float16)dv;
    }
  } else if (bi < PB + W1_ + 2*W2_) { // head1 transpose
    const int o = bi - PB - W1_ - W2_;
    for (int c = tid; c < 512; c += 256)
      h1wT[(size_t)o*512 + c] = (_Float16)h1w[(size_t)c*256 + o];
  } else {                            // zero part (B_*W2_ = 1024 floats)
    ((float4*)part)[tid] = make_float4(0.f, 0.f, 0.f, 0.f);
  }
}

// ---------------- knn v3: 32x32x16 MFMA tiles (4x pairs/MFMA) + threshold filter ----------
// R19 post-mortem of v2: 134us, VALUBusy 73%, MfmaUtil 5% -> still issue-bound on
// per-tile overhead (128 tiles/wave: addr/prefetch/acc-init/checks). Fix: K=16 fits the
// 14-dim hi/lo factorization, so mfma_f32_32x32x16_f16 covers 1024 pairs/instr.
// 512-thread blocks, 32 queries; each wave scans 1024 cands as 32 tiles of 32.
// Pass A (proven fp32 half-sample + sixteenth_of_minima) and 16-round DPP extraction
// unchanged (4 queries/wave x 8 waves). C/D map: col=lane&31, row=(reg&3)+8(reg>>2)+4(lane>>5).
#define DPP_MIN(v, ctrl)                                                        \
  { const int _t = __builtin_amdgcn_update_dpp(0, __float_as_int(v),            \
      ctrl, 0xF, 0xF, false);                                                   \
    v = fminf(v, __int_as_float(_t)); }

__device__ __forceinline__ float sixteenth_of_minima(float v) {
  float th = 0.f;
#pragma unroll
  for (int r = 0; r < 16; ++r) {
    float w = v;
    DPP_MIN(w, 0x111); DPP_MIN(w, 0x112); DPP_MIN(w, 0x114); DPP_MIN(w, 0x118);
    DPP_MIN(w, 0x142); DPP_MIN(w, 0x143);   // row_bcast15 / row_bcast31
    const float mv = __int_as_float(
        __builtin_amdgcn_readlane(__float_as_int(w), 63));
    th = mv;
    v = (v == mv) ? INFINITY : v;
  }
  return th;
}

#define KNN_DIST2(dA, dB)                                                       \
  const f2v cjx = {cj.x, cj.x}, cjy = {cj.y, cj.y},                             \
            cjz = {cj.z, cj.z}, cjw = {cj.w, cj.w};                             \
  f2v tA = cAx * cjx;                                                           \
  tA = __builtin_elementwise_fma(cAy, cjy, tA);                                 \
  tA = __builtin_elementwise_fma(cAz, cjz, tA);                                 \
  const f2v dA = __builtin_elementwise_fma(tA, m2, cAw + cjw);                  \
  f2v tB = cBx * cjx;                                                           \
  tB = __builtin_elementwise_fma(cBy, cjy, tB);                                 \
  tB = __builtin_elementwise_fma(cBz, cjz, tB);                                 \
  const f2v dB = __builtin_elementwise_fma(tB, m2, cBw + cjw);

__global__ __launch_bounds__(512) void knn_kernel(
    const float* __restrict__ coords4, const _Float16* __restrict__ qa,
    const _Float16* __restrict__ cbq, int* __restrict__ knn_idx) {
  const int tid = threadIdx.x;
  const int wid = tid >> 6;
  const int lane = tid & 63;
  const int p0 = blockIdx.x * 32;    // block of 32 never straddles batch
  const int bb = (p0 >> 13) << 13;

  __shared__ float s_Tp[32];
  __shared__ float s_Tpr[32];        // reg-order remap of s_Tp for phase 1
  __shared__ int   s_cnt[32];
  __shared__ float s_ld[32][CAP_];
  __shared__ int   s_li[32][CAP_];
  if (tid < 32) s_cnt[tid] = 0;

  // ---- pass A: fp32 packed scan of half sample -> per-query threshold bound
  const float4* cb = ((const float4*)coords4) + bb;
  const int q0 = p0 + wid * 4;
  const float4 c0 = ((const float4*)coords4)[q0+0];
  const float4 c1 = ((const float4*)coords4)[q0+1];
  const float4 c2 = ((const float4*)coords4)[q0+2];
  const float4 c3 = ((const float4*)coords4)[q0+3];
  const f2v m2 = {-2.f, -2.f};
  const f2v cAx = {c0.x, c1.x}, cAy = {c0.y, c1.y}, cAz = {c0.z, c1.z}, cAw = {c0.w, c1.w};
  const f2v cBx = {c2.x, c3.x}, cBy = {c2.y, c3.y}, cBz = {c2.z, c3.z}, cBw = {c2.w, c3.w};

  float lm0 = INFINITY, lm1 = INFINITY, lm2 = INFINITY, lm3 = INFINITY;
  for (int it = 0; it < 64; ++it) {
    const float4 cj = cb[it*64 + lane];
    KNN_DIST2(dA, dB)
    lm0 = fminf(lm0, fmaxf(dA[0], 0.f));
    lm1 = fminf(lm1, fmaxf(dA[1], 0.f));
    lm2 = fminf(lm2, fmaxf(dB[0], 0.f));
    lm3 = fminf(lm3, fmaxf(dB[1], 0.f));
  }
  const float Th0 = sixteenth_of_minima(lm0);
  const float Th1 = sixteenth_of_minima(lm1);
  const float Th2 = sixteenth_of_minima(lm2);
  const float Th3 = sixteenth_of_minima(lm3);
  if (lane == 0) {
    // margin covers fp32-vs-MFMA rounding (abs + tail-magnitude term)
    s_Tp[wid*4+0] = Th0 - c0.w + (1e-3f + 1e-5f*c0.w);
    s_Tp[wid*4+1] = Th1 - c1.w + (1e-3f + 1e-5f*c1.w);
    s_Tp[wid*4+2] = Th2 - c2.w + (1e-3f + 1e-5f*c2.w);
    s_Tp[wid*4+3] = Th3 - c3.w + (1e-3f + 1e-5f*c3.w);
  }
  __syncthreads();
  if (tid < 32) {   // remap thresholds into C/D register order per lane-half
    const int h = tid >> 4, r = tid & 15;
    s_Tpr[tid] = s_Tp[(r&3) + 8*(r>>2) + 4*h];
  }
  __syncthreads();

  // ---- phase 1: 32x32x16 MFMA scan; D[q(reg,half)][cand=tile+lrow] = -2ci.cj + xxj
  const int half = lane >> 5;
  const int lrow = lane & 31;
  float Tv[16];
  *(f4v*)&Tv[0]  = *(const f4v*)&s_Tpr[half*16 + 0];
  *(f4v*)&Tv[4]  = *(const f4v*)&s_Tpr[half*16 + 4];
  *(f4v*)&Tv[8]  = *(const f4v*)&s_Tpr[half*16 + 8];
  *(f4v*)&Tv[12] = *(const f4v*)&s_Tpr[half*16 + 12];
  const h8v afrag = *(const h8v*)(qa + (size_t)(p0 + lrow)*QAD_ + half*8);
  const int c0b = wid * 1024;                 // this wave's candidate eighth
  const _Float16* cbp = cbq + (size_t)(bb + c0b + lrow)*QAD_ + half*8;
  const f16v zacc = (f16v)0.0f;

  h8v bcur = *(const h8v*)cbp;
#pragma unroll 2
  for (int t = 0; t < 32; ++t) {
    const h8v bnxt = *(const h8v*)(cbp + (size_t)((t < 31) ? (t+1) : 0) * 32 * QAD_);
    const f16v acc = MFMA32(afrag, bcur, zacc);
    const int cidx = c0b + t*32 + lrow;
#pragma unroll
    for (int r = 0; r < 16; ++r) {
      if (acc[r] < Tv[r]) {
        const int q = (r&3) + 8*(r>>2) + 4*half;
        const int pos = atomicAdd(&s_cnt[q], 1);
        if (pos < CAP_) { s_ld[q][pos] = acc[r]; s_li[q][pos] = cidx; }
      }
    }
    bcur = bnxt;
  }
  __syncthreads();

  // ---- phase 2: per query (4 per wave), extract 16 smallest (idx tie-break)
  for (int qq = 0; qq < 4; ++qq) {
    const int q = wid*4 + qq;
    const int cnt = s_cnt[q];
    const int L = (cnt < CAP_) ? cnt : CAP_;
    float d0 = (lane      < L) ? s_ld[q][lane]      : INFINITY;
    float d1 = (lane + 64 < L) ? s_ld[q][lane + 64] : INFINITY;
    int   i0 = (lane      < L) ? s_li[q][lane]      : 0x7fffffff;
    int   i1 = (lane + 64 < L) ? s_li[q][lane + 64] : 0x7fffffff;
    int keep = 0;
    for (int r = 0; r < K_; ++r) {
      float dl = d0; int il = i0; bool s1 = false;
      if (d1 < dl || (d1 == dl && i1 < il)) { dl = d1; il = i1; s1 = true; }
      float w = dl;
      DPP_MIN(w, 0x111); DPP_MIN(w, 0x112); DPP_MIN(w, 0x114); DPP_MIN(w, 0x118);
      DPP_MIN(w, 0x142); DPP_MIN(w, 0x143);
      const float dmin = __int_as_float(
          __builtin_amdgcn_readlane(__float_as_int(w), 63));
      u64 m = __ballot(dl == dmin);
      int bi = 0x7fffffff, bl = 0;
      do {
        const int s = (int)__ffsll((unsigned long long)m) - 1; m &= m - 1;
        const int ii = __builtin_amdgcn_readlane(il, s);
        if (ii < bi) { bi = ii; bl = s; }
      } while (m);
      if (lane == bl) { if (s1) d1 = INFINITY; else d0 = INFINITY; }
      if (lane == r) keep = bi;
    }
    if (lane < K_) knn_idx[(size_t)(p0 + q)*K_ + lane] = keep;
  }
}

// ---------------- MFMA local_agg: transposed layout + 4-slot LDS dbuf + fused gmax ----------------
// r17: FOUR k-slots staged per buffer -> 4 stages, 5 barriers total (was 9).
template<int KS, int NPASS, bool GMAX>
__global__ __launch_bounds__(256) void aggm_kernel(
    const _Float16* __restrict__ fx, const int* __restrict__ knn_idx,
    const _Float16* __restrict__ midT, const _Float16* __restrict__ difT,
    const float* __restrict__ bw,
    _Float16* __restrict__ fo, const int ostr, u32* __restrict__ part) {
  const int XD  = KS*32;
  const int XDP = XD + 8;               // +16B pad per row
  const int CH  = KS*4;                 // uint4 chunks per row
  const int p0 = blockIdx.x * 16;
  const int bb = (p0 >> 13) << 13;
  const int tid = threadIdx.x;
  const int w = tid >> 6, lane = tid & 63, col = lane & 15, quad = lane >> 4;
  const int koff = quad * 8;

  __shared__ int s_idx[256];            // [point m][k]
  __shared__ _Float16 sA[2][64*(KS*32+8)];   // 2 bufs x 4 k-slots x 16 rows

  s_idx[tid] = knn_idx[p0*K_ + tid];

  // ---- C part (k-independent): A = own 16 point rows, B = difT ----
  f4v cacc[NPASS][2];
  {
    h8v Ao[KS];
    const _Float16* ap = fx + (size_t)(p0+col)*XD + koff;
#pragma unroll
    for (int kk = 0; kk < KS; ++kk) Ao[kk] = *(const h8v*)(ap + kk*32);
#pragma unroll
    for (int ps = 0; ps < NPASS; ++ps) {
      const int o0 = ps*128 + w*32;
      const _Float16* b0 = difT + (size_t)(o0 + col)*XD + koff;
      const _Float16* b1 = difT + (size_t)(o0 + 16 + col)*XD + koff;
      f4v c0 = {0.f,0.f,0.f,0.f}, c1 = {0.f,0.f,0.f,0.f};
#pragma unroll
      for (int kk = 0; kk < KS; ++kk) {
        c0 = MFMA16(Ao[kk], *(const h8v*)(b0 + kk*32), c0);
        c1 = MFMA16(Ao[kk], *(const h8v*)(b1 + kk*32), c1);
      }
      cacc[ps][0] = c0; cacc[ps][1] = c1;
    }
  }

  // ---- B fragments for ALL passes in registers ----
  h8v Bf[NPASS][2][KS];
  float bias[NPASS][2];
#pragma unroll
  for (int ps = 0; ps < NPASS; ++ps) {
    const int o0 = ps*128 + w*32;
#pragma unroll
    for (int kk = 0; kk < KS; ++kk) {
      Bf[ps][0][kk] = *(const h8v*)(midT + (size_t)(o0 + col)*XD + kk*32 + koff);
      Bf[ps][1][kk] = *(const h8v*)(midT + (size_t)(o0 + 16 + col)*XD + kk*32 + koff);
    }
    bias[ps][0] = bw[o0 + col];
    bias[ps][1] = bw[o0 + 16 + col];
  }
  __syncthreads();   // s_idx ready

  // ---- stage slots {0..3} ----  (sA row r: point r&15, slot base + (r>>4))
  for (int c = tid; c < 64*CH; c += 256) {
    const int r = c / CH, o = c - r*CH;
    *(uint4*)&sA[0][r*XDP + o*8] =
        *(const uint4*)(fx + (size_t)(bb + s_idx[((r&15)<<4) + (r>>4)])*XD + o*8);
  }
  __syncthreads();

  f4v M[NPASS][2];
#pragma unroll
  for (int ps = 0; ps < NPASS; ++ps) {
    M[ps][0] = (f4v){-INFINITY,-INFINITY,-INFINITY,-INFINITY};
    M[ps][1] = (f4v){-INFINITY,-INFINITY,-INFINITY,-INFINITY};
  }

  for (int s = 0; s < 4; ++s) {
    const int buf = s & 1;
    if (s < 3) {   // stage slots {4s+4 .. 4s+7} into the other buffer
      for (int c = tid; c < 64*CH; c += 256) {
        const int r = c / CH, o = c - r*CH;
        *(uint4*)&sA[buf^1][r*XDP + o*8] =
            *(const uint4*)(fx + (size_t)(bb + s_idx[((r&15)<<4) + 4*s+4 + (r>>4)])*XD + o*8);
      }
    }
#pragma unroll
    for (int half = 0; half < 4; ++half) {
      h8v Ac[KS];
      const _Float16* ap = &sA[buf][(half*16 + col)*XDP + koff];
#pragma unroll
      for (int kk = 0; kk < KS; ++kk) Ac[kk] = *(const h8v*)(ap + kk*32);
#pragma unroll
      for (int ps = 0; ps < NPASS; ++ps) {
        f4v d0 = {0.f,0.f,0.f,0.f}, d1 = {0.f,0.f,0.f,0.f};
#pragma unroll
        for (int kk = 0; kk < KS; ++kk) {
          d0 = MFMA16(Ac[kk], Bf[ps][0][kk], d0);
          d1 = MFMA16(Ac[kk], Bf[ps][1][kk], d1);
        }
#pragma unroll
        for (int e = 0; e < 4; ++e) {
          M[ps][0][e] = fmaxf(M[ps][0][e], d0[e]);
          M[ps][1][e] = fmaxf(M[ps][1][e], d1[e]);
        }
      }
    }
    if (s < 3) __syncthreads();   // staged visible; readers done before overwrite
  }

  // ---- epilogue: out[p][o] = max(M + C + bias, 0); lane holds rows quad*4+reg ----
  const int prow = p0 + (quad << 2);
  const int bq = p0 >> 13;
#pragma unroll
  for (int ps = 0; ps < NPASS; ++ps) {
    const int o0 = ps*128 + w*32;
    const int oa = o0 + col, ob = oa + 16;
    float v0[4], v1[4];
#pragma unroll
    for (int reg = 0; reg < 4; ++reg) {
      v0[reg] = fmaxf(M[ps][0][reg] + cacc[ps][0][reg] + bias[ps][0], 0.f);
      v1[reg] = fmaxf(M[ps][1][reg] + cacc[ps][1][reg] + bias[ps][1], 0.f);
      fo[(size_t)(prow+reg)*ostr + oa] = (_Float16)v0[reg];
      fo[(size_t)(prow+reg)*ostr + ob] = (_Float16)v1[reg];
    }
    if (GMAX) {   // block-local max over 16 points, then one atomic per output
      float bm0 = fmaxf(fmaxf(v0[0], v0[1]), fmaxf(v0[2], v0[3]));
      float bm1 = fmaxf(fmaxf(v1[0], v1[1]), fmaxf(v1[2], v1[3]));
      bm0 = fmaxf(bm0, __shfl_xor(bm0, 16, 64));
      bm0 = fmaxf(bm0, __shfl_xor(bm0, 32, 64));
      bm1 = fmaxf(bm1, __shfl_xor(bm1, 16, 64));
      bm1 = fmaxf(bm1, __shfl_xor(bm1, 32, 64));
      if (quad == 0) {
        atomicMax(part + bq*W2_ + oa, __float_as_uint(bm0));
        atomicMax(part + bq*W2_ + ob, __float_as_uint(bm1));
      }
    }
  }
}

// ---------------- glob FC from fused-max part -> g2h fp16 ----------------
__global__ __launch_bounds__(256) void gfc_kernel(
    const float* __restrict__ part, const float* __restrict__ gw,
    const float* __restrict__ gb, _Float16* __restrict__ g2h) {
  const int b = blockIdx.x;
  const int o = threadIdx.x;
  __shared__ float s_g[W2_];
  s_g[o] = part[b*W2_ + o];   // bits from atomicMax(u32) == float bits (>=0)
  __syncthreads();
  float acc = gb[o];
  for (int d = 0; d < W2_; ++d) acc += s_g[d]*gw[d*W2_ + o];
  g2h[b*W2_ + o] = (_Float16)fmaxf(acc, 0.f);
}

// ---------------- head: 32 points/block MFMA GEMM + tiny second layer ----------------
__global__ __launch_bounds__(256) void headm_kernel(
    const _Float16* __restrict__ f2h, const _Float16* __restrict__ g2h,
    const _Float16* __restrict__ h1wT, const float* __restrict__ h1b,
    const float* __restrict__ h2w, const float* __restrict__ h2b,
    const float* __restrict__ x,
    const float* __restrict__ thresh, const float* __restrict__ sharp,
    const float* __restrict__ scale,
    float* __restrict__ out) {
  const int p0 = blockIdx.x * 32;
  const int b = p0 >> 13;
  const int tid = threadIdx.x;
  const int w = tid >> 6, lane = tid & 63, col = lane & 15, quad = lane >> 4;

  __shared__ _Float16 sA[32*520];   // 32 points x 512 (padded to 520)
  __shared__ float    sh[32*260];   // relu(h1) f32

  for (int t = tid; t < 32*32; t += 256) {       // f2h part (16B chunks)
    const int r = t >> 5, cc = (t & 31) * 8;
    *(uint4*)&sA[r*520 + cc] = *(const uint4*)&f2h[(size_t)(p0+r)*W2_ + cc];
  }
  for (int t = tid; t < 32*32; t += 256) {       // g2h broadcast part
    const int r = t >> 5, cc = (t & 31) * 8;
    *(uint4*)&sA[r*520 + 256 + cc] = *(const uint4*)&g2h[b*W2_ + cc];
  }
  __syncthreads();

  f4v acc[2][4];
#pragma unroll
  for (int r = 0; r < 2; ++r)
#pragma unroll
    for (int t = 0; t < 4; ++t) acc[r][t] = (f4v){0.f,0.f,0.f,0.f};

  for (int kk = 0; kk < 16; ++kk) {
    const h8v a0 = *(const h8v*)&sA[col*520 + kk*32 + quad*8];
    const h8v a1 = *(const h8v*)&sA[(16+col)*520 + kk*32 + quad*8];
#pragma unroll
    for (int t = 0; t < 4; ++t) {
      const h8v bt = *(const h8v*)&h1wT[(size_t)(w*64 + t*16 + col)*512 + kk*32 + quad*8];
      acc[0][t] = MFMA16(a0, bt, acc[0][t]);
      acc[1][t] = MFMA16(a1, bt, acc[1][t]);
    }
  }
#pragma unroll
  for (int r = 0; r < 2; ++r)
#pragma unroll
    for (int t = 0; t < 4; ++t) {
      const int o = w*64 + t*16 + col;
      const float bv = h1b[o];
#pragma unroll
      for (int reg = 0; reg < 4; ++reg)
        sh[(r*16 + quad*4 + reg)*260 + o] = fmaxf(acc[r][t][reg] + bv, 0.f);
    }
  __syncthreads();

  if (tid < 96) {
    const int pp = tid / 3, c = tid % 3;
    float s = h2b[c];
    for (int d = 0; d < 256; ++d) s += sh[pp*260 + d] * h2w[d*3 + c];
    if (c == 0) {
      const float hag = x[(size_t)(p0+pp)*4 + 3];
      s += scale[0] / (1.f + expf(-sharp[0]*(thresh[0] - hag)));
    }
    out[(size_t)(p0+pp)*3 + c] = s;
  }
}

// ---------------- launch ----------------
extern "C" void kernel_launch(void* const* d_in, const int* in_sizes, int n_in,
                              void* d_out, int out_size, void* d_ws, size_t ws_size,
                              hipStream_t stream) {
  const float* x       = (const float*)d_in[0];
  const float* hmix_a  = (const float*)d_in[1];
  const float* hmix_b  = (const float*)d_in[2];
  const float* hmix_c  = (const float*)d_in[3];
  const float* stem_w  = (const float*)d_in[4];
  const float* stem_b  = (const float*)d_in[5];
  const float* b1_w    = (const float*)d_in[6];
  const float* b1_b    = (const float*)d_in[7];
  const float* b2_w    = (const float*)d_in[8];
  const float* b2_b    = (const float*)d_in[9];
  const float* glob_w  = (const float*)d_in[10];
  const float* glob_b  = (const float*)d_in[11];
  const float* head1_w = (const float*)d_in[12];
  const float* head1_b = (const float*)d_in[13];
  const float* head2_w = (const float*)d_in[14];
  const float* head2_b = (const float*)d_in[15];
  const float* thresh  = (const float*)d_in[16];
  const float* sharp   = (const float*)d_in[17];
  const float* scale   = (const float*)d_in[18];
  float* out = (float*)d_out;

  char* base = (char*)d_ws;
  float*     coords4 = (float*)    (base + 0);          // 512 KB
  int*       idxb    = (int*)      (base + 524288);     // 2 MB
  _Float16*  fx0     = (_Float16*) (base + 2621440);    // 6 MB   (32768*96*2)
  _Float16*  fx1     = (_Float16*) (base + 8912896);    // 10 MB  (32768*160*2)
  _Float16*  f2h     = (_Float16*) (base + 19398656);   // 16 MB  (32768*256*2)
  // qa/cbq alias the f2h region: consumed by knn, f2h written only later (aggm2)
  _Float16*  qa      = (_Float16*) (base + 19398656);   // 1 MB   (32768*16*2)
  _Float16*  cbq     = (_Float16*) (base + 20447232);   // 1 MB
  _Float16*  w1m     = (_Float16*) (base + 36175872);   // 24 KB  (128*96*2)
  _Float16*  w1d     = (_Float16*) (base + 36200448);   // 24 KB
  _Float16*  w2m     = (_Float16*) (base + 36225024);   // 80 KB  (256*160*2)
  _Float16*  w2d     = (_Float16*) (base + 36306944);   // 80 KB
  _Float16*  h1wT    = (_Float16*) (base + 36388864);   // 256 KB (256*512*2)
  float*     part    = (float*)    (base + 36651008);   // 4 KB (4*256 f32, fused max)
  _Float16*  g2h     = (_Float16*) (base + 36782080);   // 2 KB
  const int NP = B_ * N_;   // 32768 points

  prep_kernel<<<NP/4 + W1_ + 2*W2_ + 1, 256, 0, stream>>>(
      x, stem_w, stem_b, hmix_a, hmix_b, hmix_c, coords4, fx0, fx1,
      b1_w, b2_w, head1_w, w1m, w1d, w2m, w2d, h1wT, qa, cbq, part);
  knn_kernel<<<NP/32, 512, 0, stream>>>(coords4, qa, cbq, idxb);
  aggm_kernel<3, 1, false><<<NP/16, 256, 0, stream>>>(
      fx0, idxb, w1m, w1d, b1_b, fx1, X1_, (u32*)0);
  aggm_kernel<5, 2, true><<<NP/16, 256, 0, stream>>>(
      fx1, idxb, w2m, w2d, b2_b, f2h, W2_, (u32*)part);
  gfc_kernel<<<B_, 256, 0, stream>>>(part, glob_w, glob_b, g2h);
  headm_kernel<<<NP/32, 256, 0, stream>>>(f2h, g2h, h1wT, head1_b, head2_w, head2_b,
                                          x, thresh, sharp, scale, out);
}

// Round 3
// 375.164 us; speedup vs baseline: 1.0961x; 1.0010x over previous
//
#include <hip/hip_runtime.h>
#include <math.h>

typedef unsigned long long u64;
typedef unsigned int u32;
typedef _Float16 h8v __attribute__((ext_vector_type(8)));  // 8 fp16 (4 VGPRs)
typedef float    f4v __attribute__((ext_vector_type(4)));  // MFMA acc (16x16)
typedef float    f16v __attribute__((ext_vector_type(16))); // MFMA acc (32x32)
typedef float    f2v __attribute__((ext_vector_type(2)));  // v_pk_*_f32 pair

#define MFMA16(a,b,c) __builtin_amdgcn_mfma_f32_16x16x32_f16(a, b, c, 0, 0, 0)
#define MFMA32(a,b,c) __builtin_amdgcn_mfma_f32_32x32x16_f16(a, b, c, 0, 0, 0)

#define B_ 4
#define N_ 8192
#define K_ 16
#define W0_ 64
#define W1_ 128
#define W2_ 256
#define X0_ 96   // padded K-dim layer-1 inputs (64 feat + 3 coord + 29 zero)
#define X1_ 160  // padded K-dim layer-2 inputs (128 feat + 3 coord + 29 zero)
#define QAD_ 16  // knn MFMA operand row width (14 used dims + 2 zero, K=16)
#define CAP_ 128 // per-query knn candidate-list capacity (mean ~36, +10 sigma)

// ---------------- merged prep: points + weight conversions + part zeroing ----------------
__global__ __launch_bounds__(256) void prep_kernel(
    const float* __restrict__ x,
    const float* __restrict__ stem_w, const float* __restrict__ stem_b,
    const float* __restrict__ hmix_a, const float* __restrict__ hmix_b,
    const float* __restrict__ hmix_c,
    float* __restrict__ coords4, _Float16* __restrict__ fx0,
    _Float16* __restrict__ fx1,
    const float* __restrict__ b1_w, const float* __restrict__ b2_w,
    const float* __restrict__ h1w,
    _Float16* __restrict__ w1m, _Float16* __restrict__ w1d,
    _Float16* __restrict__ w2m, _Float16* __restrict__ w2d,
    _Float16* __restrict__ h1wT,
    _Float16* __restrict__ qa, _Float16* __restrict__ cbq,
    float* __restrict__ part) {
  const int bi = blockIdx.x;
  const int tid = threadIdx.x;
  const int PB = (B_*N_)/4;          // 8192
  if (bi < PB) {
    const int p = bi * 4 + (tid >> 6);
    const int o = tid & 63;
    const float x0 = x[p*4+0], x1 = x[p*4+1], x2 = x[p*4+2], x3 = x[p*4+3];
    const float z = hmix_a[0]*x2 + hmix_b[0]*x3 + hmix_c[0];
    float acc = stem_b[o] + x0*stem_w[0*W0_+o] + x1*stem_w[1*W0_+o]
              + x2*stem_w[2*W0_+o] + x3*stem_w[3*W0_+o];
    fx0[p*X0_+o] = (_Float16)fmaxf(acc, 0.f);
    if (o < 32) {   // tail: 3 coords + 29 zeros (both layers' inputs)
      const float tv = (o==0) ? x0 : (o==1) ? x1 : (o==2) ? z : 0.f;
      fx0[p*X0_+W0_+o] = (_Float16)tv;
      fx1[(size_t)p*X1_+W1_+o] = (_Float16)tv;
    }
    if (o == 0) {
      const float xx = x0*x0 + x1*x1 + z*z;
      ((float4*)coords4)[p] = make_float4(x0, x1, z, xx);
    } else if (o == 1) {
      // knn A-operand row (K=16): [hi3, lo3, hi3, lo3, 1, 1, 0, 0] (hi/lo fp16 split)
      const _Float16 hx = (_Float16)x0, hy = (_Float16)x1, hz = (_Float16)z;
      const _Float16 lx = (_Float16)(x0 - (float)hx);
      const _Float16 ly = (_Float16)(x1 - (float)hy);
      const _Float16 lz = (_Float16)(z  - (float)hz);
      const _Float16 one = (_Float16)1.f, Z = (_Float16)0.f;
      h8v a0 = {hx, hy, hz, lx, ly, lz, hx, hy};
      h8v a1 = {hz, lx, ly, lz, one, one, Z, Z};
      *(h8v*)(qa + (size_t)p*QAD_)      = a0;
      *(h8v*)(qa + (size_t)p*QAD_ + 8)  = a1;
    } else if (o == 2) {
      // knn B-operand row (K=16): [-2hi3, -2lo3, -2lo3, -2hi3, xxhi, xxlo, 0, 0]
      // dot(A_i, B_j) = -2 (hi_i+lo_i).(hi_j+lo_j) + xx_j  (products exact in fp32 acc)
      const _Float16 hx = (_Float16)x0, hy = (_Float16)x1, hz = (_Float16)z;
      const _Float16 lx = (_Float16)(x0 - (float)hx);
      const _Float16 ly = (_Float16)(x1 - (float)hy);
      const _Float16 lz = (_Float16)(z  - (float)hz);
      const float xx = x0*x0 + x1*x1 + z*z;
      const _Float16 xh = (_Float16)xx;
      const _Float16 xl = (_Float16)(xx - (float)xh);
      const _Float16 nhx = (_Float16)(-2.f*(float)hx);
      const _Float16 nhy = (_Float16)(-2.f*(float)hy);
      const _Float16 nhz = (_Float16)(-2.f*(float)hz);
      const _Float16 nlx = (_Float16)(-2.f*(float)lx);
      const _Float16 nly = (_Float16)(-2.f*(float)ly);
      const _Float16 nlz = (_Float16)(-2.f*(float)lz);
      const _Float16 Z = (_Float16)0.f;
      h8v b0 = {nhx, nhy, nhz, nlx, nly, nlz, nlx, nly};
      h8v b1 = {nlz, nhx, nhy, nhz, xh, xl, Z, Z};
      *(h8v*)(cbq + (size_t)p*QAD_)      = b0;
      *(h8v*)(cbq + (size_t)p*QAD_ + 8)  = b1;
    }
  } else if (bi < PB + W1_) {        // wconv layer1
    const int o = bi - PB, c = tid;
    if (c < X0_) {
      float mv = 0.f, dv = 0.f;
      if (c < W0_)        { const float wm = b1_w[(W0_+c)*W1_+o]; mv = wm; dv = b1_w[c*W1_+o] - wm; }
      else if (c < W0_+3) { const float wp = b1_w[(2*W0_+(c-W0_))*W1_+o]; mv = wp; dv = -wp; }
      w1m[o*X0_+c] = (_Float16)mv;
      w1d[o*X0_+c] = (_Float16)dv;
    }
  } else if (bi < PB + W1_ + W2_) {  // wconv layer2
    const int o = bi - PB - W1_, c = tid;
    if (c < X1_) {
      float mv = 0.f, dv = 0.f;
      if (c < W1_)        { const float wm = b2_w[(W1_+c)*W2_+o]; mv = wm; dv = b2_w[c*W2_+o] - wm; }
      else if (c < W1_+3) { const float wp = b2_w[(2*W1_+(c-W1_))*W2_+o]; mv = wp; dv = -wp; }
      w2m[o*X1_+c] = (_Float16)mv;
      w2d[o*X1_+c] = (_Float16)dv;
    }
  } else if (bi < PB + W1_ + 2*W2_) { // head1 transpose
    const int o = bi - PB - W1_ - W2_;
    for (int c = tid; c < 512; c += 256)
      h1wT[(size_t)o*512 + c] = (_Float16)h1w[(size_t)c*256 + o];
  } else {                            // zero part (B_*W2_ = 1024 floats)
    ((float4*)part)[tid] = make_float4(0.f, 0.f, 0.f, 0.f);
  }
}

// ---------------- knn v4: 32x32x16 MFMA + ballot-guarded hit paths ----------
// R20 post-mortem of v3: 114us, VALU instr/wave ~13.7K (barely down from v2) ->
// the 16 per-reg hit bodies were exec-predicated straight-line code, issued every
// tile regardless of hits (~6K dead instr/wave). Fix: uniform __ballot guard ->
// s_cbranch_execz skips the body; only ~4.5 of 512 checks/tile take it.
// Also: {dist,idx} packed as float2 -> one ds_write_b64; cidx sunk into the branch.
// Selection semantics identical to v3 (same thresholds, margin, tie-break).
#define DPP_MIN(v, ctrl)                                                        \
  { const int _t = __builtin_amdgcn_update_dpp(0, __float_as_int(v),            \
      ctrl, 0xF, 0xF, false);                                                   \
    v = fminf(v, __int_as_float(_t)); }

__device__ __forceinline__ float sixteenth_of_minima(float v) {
  float th = 0.f;
#pragma unroll
  for (int r = 0; r < 16; ++r) {
    float w = v;
    DPP_MIN(w, 0x111); DPP_MIN(w, 0x112); DPP_MIN(w, 0x114); DPP_MIN(w, 0x118);
    DPP_MIN(w, 0x142); DPP_MIN(w, 0x143);   // row_bcast15 / row_bcast31
    const float mv = __int_as_float(
        __builtin_amdgcn_readlane(__float_as_int(w), 63));
    th = mv;
    v = (v == mv) ? INFINITY : v;
  }
  return th;
}

#define KNN_DIST2(dA, dB)                                                       \
  const f2v cjx = {cj.x, cj.x}, cjy = {cj.y, cj.y},                             \
            cjz = {cj.z, cj.z}, cjw = {cj.w, cj.w};                             \
  f2v tA = cAx * cjx;                                                           \
  tA = __builtin_elementwise_fma(cAy, cjy, tA);                                 \
  tA = __builtin_elementwise_fma(cAz, cjz, tA);                                 \
  const f2v dA = __builtin_elementwise_fma(tA, m2, cAw + cjw);                  \
  f2v tB = cBx * cjx;                                                           \
  tB = __builtin_elementwise_fma(cBy, cjy, tB);                                 \
  tB = __builtin_elementwise_fma(cBz, cjz, tB);                                 \
  const f2v dB = __builtin_elementwise_fma(tB, m2, cBw + cjw);

__global__ __launch_bounds__(512) void knn_kernel(
    const float* __restrict__ coords4, const _Float16* __restrict__ qa,
    const _Float16* __restrict__ cbq, int* __restrict__ knn_idx) {
  const int tid = threadIdx.x;
  const int wid = tid >> 6;
  const int lane = tid & 63;
  const int p0 = blockIdx.x * 32;    // block of 32 never straddles batch
  const int bb = (p0 >> 13) << 13;

  __shared__ float  s_Tp[32];
  __shared__ float  s_Tpr[32];       // reg-order remap of s_Tp for phase 1
  __shared__ int    s_cnt[32];
  __shared__ float2 s_pr[32][CAP_];  // {dist, idx-bits} pairs, ds_*_b64
  if (tid < 32) s_cnt[tid] = 0;

  // ---- pass A: fp32 packed scan of half sample -> per-query threshold bound
  const float4* cb = ((const float4*)coords4) + bb;
  const int q0 = p0 + wid * 4;
  const float4 c0 = ((const float4*)coords4)[q0+0];
  const float4 c1 = ((const float4*)coords4)[q0+1];
  const float4 c2 = ((const float4*)coords4)[q0+2];
  const float4 c3 = ((const float4*)coords4)[q0+3];
  const f2v m2 = {-2.f, -2.f};
  const f2v cAx = {c0.x, c1.x}, cAy = {c0.y, c1.y}, cAz = {c0.z, c1.z}, cAw = {c0.w, c1.w};
  const f2v cBx = {c2.x, c3.x}, cBy = {c2.y, c3.y}, cBz = {c2.z, c3.z}, cBw = {c2.w, c3.w};

  float lm0 = INFINITY, lm1 = INFINITY, lm2 = INFINITY, lm3 = INFINITY;
  for (int it = 0; it < 64; ++it) {
    const float4 cj = cb[it*64 + lane];
    KNN_DIST2(dA, dB)
    lm0 = fminf(lm0, fmaxf(dA[0], 0.f));
    lm1 = fminf(lm1, fmaxf(dA[1], 0.f));
    lm2 = fminf(lm2, fmaxf(dB[0], 0.f));
    lm3 = fminf(lm3, fmaxf(dB[1], 0.f));
  }
  const float Th0 = sixteenth_of_minima(lm0);
  const float Th1 = sixteenth_of_minima(lm1);
  const float Th2 = sixteenth_of_minima(lm2);
  const float Th3 = sixteenth_of_minima(lm3);
  if (lane == 0) {
    // margin covers fp32-vs-MFMA rounding (abs + tail-magnitude term)
    s_Tp[wid*4+0] = Th0 - c0.w + (1e-3f + 1e-5f*c0.w);
    s_Tp[wid*4+1] = Th1 - c1.w + (1e-3f + 1e-5f*c1.w);
    s_Tp[wid*4+2] = Th2 - c2.w + (1e-3f + 1e-5f*c2.w);
    s_Tp[wid*4+3] = Th3 - c3.w + (1e-3f + 1e-5f*c3.w);
  }
  __syncthreads();
  if (tid < 32) {   // remap thresholds into C/D register order per lane-half
    const int h = tid >> 4, r = tid & 15;
    s_Tpr[tid] = s_Tp[(r&3) + 8*(r>>2) + 4*h];
  }
  __syncthreads();

  // ---- phase 1: 32x32x16 MFMA scan; D[q(reg,half)][cand=tile+lrow] = -2ci.cj + xxj
  const int half = lane >> 5;
  const int h4 = half << 2;
  const int lrow = lane & 31;
  float Tv[16];
  *(f4v*)&Tv[0]  = *(const f4v*)&s_Tpr[half*16 + 0];
  *(f4v*)&Tv[4]  = *(const f4v*)&s_Tpr[half*16 + 4];
  *(f4v*)&Tv[8]  = *(const f4v*)&s_Tpr[half*16 + 8];
  *(f4v*)&Tv[12] = *(const f4v*)&s_Tpr[half*16 + 12];
  const h8v afrag = *(const h8v*)(qa + (size_t)(p0 + lrow)*QAD_ + half*8);
  const int c0b = wid * 1024;                 // this wave's candidate eighth
  const int cibase = c0b + lrow;
  const _Float16* cbp = cbq + (size_t)(bb + c0b + lrow)*QAD_ + half*8;
  const f16v zacc = (f16v)0.0f;

  h8v bcur = *(const h8v*)cbp;
#pragma unroll 2
  for (int t = 0; t < 32; ++t) {
    const h8v bnxt = *(const h8v*)(cbp + (size_t)((t < 31) ? (t+1) : 0) * 32 * QAD_);
    const f16v acc = MFMA32(afrag, bcur, zacc);
#pragma unroll
    for (int r = 0; r < 16; ++r) {
      const bool c = acc[r] < Tv[r];
      const u64 m = __ballot(c);
      if (m) {                               // uniform branch: skip when no lane hits
        const int q = ((r&3) + 8*(r>>2)) + h4;
        if (c) {
          const int pos = atomicAdd(&s_cnt[q], 1);
          if (pos < CAP_)
            s_pr[q][pos] = make_float2(acc[r], __int_as_float(cibase + t*32));
        }
      }
    }
    bcur = bnxt;
  }
  __syncthreads();

  // ---- phase 2: per query (4 per wave), extract 16 smallest (idx tie-break)
  for (int qq = 0; qq < 4; ++qq) {
    const int q = wid*4 + qq;
    const int cnt = s_cnt[q];
    const int L = (cnt < CAP_) ? cnt : CAP_;
    float d0 = INFINITY, d1 = INFINITY;
    int   i0 = 0x7fffffff, i1 = 0x7fffffff;
    if (lane < L)      { const float2 e = s_pr[q][lane];      d0 = e.x; i0 = __float_as_int(e.y); }
    if (lane + 64 < L) { const float2 e = s_pr[q][lane + 64]; d1 = e.x; i1 = __float_as_int(e.y); }
    int keep = 0;
    for (int r = 0; r < K_; ++r) {
      float dl = d0; int il = i0; bool s1 = false;
      if (d1 < dl || (d1 == dl && i1 < il)) { dl = d1; il = i1; s1 = true; }
      float w = dl;
      DPP_MIN(w, 0x111); DPP_MIN(w, 0x112); DPP_MIN(w, 0x114); DPP_MIN(w, 0x118);
      DPP_MIN(w, 0x142); DPP_MIN(w, 0x143);
      const float dmin = __int_as_float(
          __builtin_amdgcn_readlane(__float_as_int(w), 63));
      u64 m = __ballot(dl == dmin);
      int bi = 0x7fffffff, bl = 0;
      do {
        const int s = (int)__ffsll((unsigned long long)m) - 1; m &= m - 1;
        const int ii = __builtin_amdgcn_readlane(il, s);
        if (ii < bi) { bi = ii; bl = s; }
      } while (m);
      if (lane == bl) { if (s1) d1 = INFINITY; else d0 = INFINITY; }
      if (lane == r) keep = bi;
    }
    if (lane < K_) knn_idx[(size_t)(p0 + q)*K_ + lane] = keep;
  }
}

// ---------------- MFMA local_agg: transposed layout + 4-slot LDS dbuf + fused gmax ----------------
// r17: FOUR k-slots staged per buffer -> 4 stages, 5 barriers total (was 9).
template<int KS, int NPASS, bool GMAX>
__global__ __launch_bounds__(256) void aggm_kernel(
    const _Float16* __restrict__ fx, const int* __restrict__ knn_idx,
    const _Float16* __restrict__ midT, const _Float16* __restrict__ difT,
    const float* __restrict__ bw,
    _Float16* __restrict__ fo, const int ostr, u32* __restrict__ part) {
  const int XD  = KS*32;
  const int XDP = XD + 8;               // +16B pad per row
  const int CH  = KS*4;                 // uint4 chunks per row
  const int p0 = blockIdx.x * 16;
  const int bb = (p0 >> 13) << 13;
  const int tid = threadIdx.x;
  const int w = tid >> 6, lane = tid & 63, col = lane & 15, quad = lane >> 4;
  const int koff = quad * 8;

  __shared__ int s_idx[256];            // [point m][k]
  __shared__ _Float16 sA[2][64*(KS*32+8)];   // 2 bufs x 4 k-slots x 16 rows

  s_idx[tid] = knn_idx[p0*K_ + tid];

  // ---- C part (k-independent): A = own 16 point rows, B = difT ----
  f4v cacc[NPASS][2];
  {
    h8v Ao[KS];
    const _Float16* ap = fx + (size_t)(p0+col)*XD + koff;
#pragma unroll
    for (int kk = 0; kk < KS; ++kk) Ao[kk] = *(const h8v*)(ap + kk*32);
#pragma unroll
    for (int ps = 0; ps < NPASS; ++ps) {
      const int o0 = ps*128 + w*32;
      const _Float16* b0 = difT + (size_t)(o0 + col)*XD + koff;
      const _Float16* b1 = difT + (size_t)(o0 + 16 + col)*XD + koff;
      f4v c0 = {0.f,0.f,0.f,0.f}, c1 = {0.f,0.f,0.f,0.f};
#pragma unroll
      for (int kk = 0; kk < KS; ++kk) {
        c0 = MFMA16(Ao[kk], *(const h8v*)(b0 + kk*32), c0);
        c1 = MFMA16(Ao[kk], *(const h8v*)(b1 + kk*32), c1);
      }
      cacc[ps][0] = c0; cacc[ps][1] = c1;
    }
  }

  // ---- B fragments for ALL passes in registers ----
  h8v Bf[NPASS][2][KS];
  float bias[NPASS][2];
#pragma unroll
  for (int ps = 0; ps < NPASS; ++ps) {
    const int o0 = ps*128 + w*32;
#pragma unroll
    for (int kk = 0; kk < KS; ++kk) {
      Bf[ps][0][kk] = *(const h8v*)(midT + (size_t)(o0 + col)*XD + kk*32 + koff);
      Bf[ps][1][kk] = *(const h8v*)(midT + (size_t)(o0 + 16 + col)*XD + kk*32 + koff);
    }
    bias[ps][0] = bw[o0 + col];
    bias[ps][1] = bw[o0 + 16 + col];
  }
  __syncthreads();   // s_idx ready

  // ---- stage slots {0..3} ----  (sA row r: point r&15, slot base + (r>>4))
  for (int c = tid; c < 64*CH; c += 256) {
    const int r = c / CH, o = c - r*CH;
    *(uint4*)&sA[0][r*XDP + o*8] =
        *(const uint4*)(fx + (size_t)(bb + s_idx[((r&15)<<4) + (r>>4)])*XD + o*8);
  }
  __syncthreads();

  f4v M[NPASS][2];
#pragma unroll
  for (int ps = 0; ps < NPASS; ++ps) {
    M[ps][0] = (f4v){-INFINITY,-INFINITY,-INFINITY,-INFINITY};
    M[ps][1] = (f4v){-INFINITY,-INFINITY,-INFINITY,-INFINITY};
  }

  for (int s = 0; s < 4; ++s) {
    const int buf = s & 1;
    if (s < 3) {   // stage slots {4s+4 .. 4s+7} into the other buffer
      for (int c = tid; c < 64*CH; c += 256) {
        const int r = c / CH, o = c - r*CH;
        *(uint4*)&sA[buf^1][r*XDP + o*8] =
            *(const uint4*)(fx + (size_t)(bb + s_idx[((r&15)<<4) + 4*s+4 + (r>>4)])*XD + o*8);
      }
    }
#pragma unroll
    for (int half = 0; half < 4; ++half) {
      h8v Ac[KS];
      const _Float16* ap = &sA[buf][(half*16 + col)*XDP + koff];
#pragma unroll
      for (int kk = 0; kk < KS; ++kk) Ac[kk] = *(const h8v*)(ap + kk*32);
#pragma unroll
      for (int ps = 0; ps < NPASS; ++ps) {
        f4v d0 = {0.f,0.f,0.f,0.f}, d1 = {0.f,0.f,0.f,0.f};
#pragma unroll
        for (int kk = 0; kk < KS; ++kk) {
          d0 = MFMA16(Ac[kk], Bf[ps][0][kk], d0);
          d1 = MFMA16(Ac[kk], Bf[ps][1][kk], d1);
        }
#pragma unroll
        for (int e = 0; e < 4; ++e) {
          M[ps][0][e] = fmaxf(M[ps][0][e], d0[e]);
          M[ps][1][e] = fmaxf(M[ps][1][e], d1[e]);
        }
      }
    }
    if (s < 3) __syncthreads();   // staged visible; readers done before overwrite
  }

  // ---- epilogue: out[p][o] = max(M + C + bias, 0); lane holds rows quad*4+reg ----
  const int prow = p0 + (quad << 2);
  const int bq = p0 >> 13;
#pragma unroll
  for (int ps = 0; ps < NPASS; ++ps) {
    const int o0 = ps*128 + w*32;
    const int oa = o0 + col, ob = oa + 16;
    float v0[4], v1[4];
#pragma unroll
    for (int reg = 0; reg < 4; ++reg) {
      v0[reg] = fmaxf(M[ps][0][reg] + cacc[ps][0][reg] + bias[ps][0], 0.f);
      v1[reg] = fmaxf(M[ps][1][reg] + cacc[ps][1][reg] + bias[ps][1], 0.f);
      fo[(size_t)(prow+reg)*ostr + oa] = (_Float16)v0[reg];
      fo[(size_t)(prow+reg)*ostr + ob] = (_Float16)v1[reg];
    }
    if (GMAX) {   // block-local max over 16 points, then one atomic per output
      float bm0 = fmaxf(fmaxf(v0[0], v0[1]), fmaxf(v0[2], v0[3]));
      float bm1 = fmaxf(fmaxf(v1[0], v1[1]), fmaxf(v1[2], v1[3]));
      bm0 = fmaxf(bm0, __shfl_xor(bm0, 16, 64));
      bm0 = fmaxf(bm0, __shfl_xor(bm0, 32, 64));
      bm1 = fmaxf(bm1, __shfl_xor(bm1, 16, 64));
      bm1 = fmaxf(bm1, __shfl_xor(bm1, 32, 64));
      if (quad == 0) {
        atomicMax(part + bq*W2_ + oa, __float_as_uint(bm0));
        atomicMax(part + bq*W2_ + ob, __float_as_uint(bm1));
      }
    }
  }
}

// ---------------- glob FC from fused-max part -> g2h fp16 ----------------
__global__ __launch_bounds__(256) void gfc_kernel(
    const float* __restrict__ part, const float* __restrict__ gw,
    const float* __restrict__ gb, _Float16* __restrict__ g2h) {
  const int b = blockIdx.x;
  const int o = threadIdx.x;
  __shared__ float s_g[W2_];
  s_g[o] = part[b*W2_ + o];   // bits from atomicMax(u32) == float bits (>=0)
  __syncthreads();
  float acc = gb[o];
  for (int d = 0; d < W2_; ++d) acc += s_g[d]*gw[d*W2_ + o];
  g2h[b*W2_ + o] = (_Float16)fmaxf(acc, 0.f);
}

// ---------------- head: 32 points/block MFMA GEMM + tiny second layer ----------------
__global__ __launch_bounds__(256) void headm_kernel(
    const _Float16* __restrict__ f2h, const _Float16* __restrict__ g2h,
    const _Float16* __restrict__ h1wT, const float* __restrict__ h1b,
    const float* __restrict__ h2w, const float* __restrict__ h2b,
    const float* __restrict__ x,
    const float* __restrict__ thresh, const float* __restrict__ sharp,
    const float* __restrict__ scale,
    float* __restrict__ out) {
  const int p0 = blockIdx.x * 32;
  const int b = p0 >> 13;
  const int tid = threadIdx.x;
  const int w = tid >> 6, lane = tid & 63, col = lane & 15, quad = lane >> 4;

  __shared__ _Float16 sA[32*520];   // 32 points x 512 (padded to 520)
  __shared__ float    sh[32*260];   // relu(h1) f32

  for (int t = tid; t < 32*32; t += 256) {       // f2h part (16B chunks)
    const int r = t >> 5, cc = (t & 31) * 8;
    *(uint4*)&sA[r*520 + cc] = *(const uint4*)&f2h[(size_t)(p0+r)*W2_ + cc];
  }
  for (int t = tid; t < 32*32; t += 256) {       // g2h broadcast part
    const int r = t >> 5, cc = (t & 31) * 8;
    *(uint4*)&sA[r*520 + 256 + cc] = *(const uint4*)&g2h[b*W2_ + cc];
  }
  __syncthreads();

  f4v acc[2][4];
#pragma unroll
  for (int r = 0; r < 2; ++r)
#pragma unroll
    for (int t = 0; t < 4; ++t) acc[r][t] = (f4v){0.f,0.f,0.f,0.f};

  for (int kk = 0; kk < 16; ++kk) {
    const h8v a0 = *(const h8v*)&sA[col*520 + kk*32 + quad*8];
    const h8v a1 = *(const h8v*)&sA[(16+col)*520 + kk*32 + quad*8];
#pragma unroll
    for (int t = 0; t < 4; ++t) {
      const h8v bt = *(const h8v*)&h1wT[(size_t)(w*64 + t*16 + col)*512 + kk*32 + quad*8];
      acc[0][t] = MFMA16(a0, bt, acc[0][t]);
      acc[1][t] = MFMA16(a1, bt, acc[1][t]);
    }
  }
#pragma unroll
  for (int r = 0; r < 2; ++r)
#pragma unroll
    for (int t = 0; t < 4; ++t) {
      const int o = w*64 + t*16 + col;
      const float bv = h1b[o];
#pragma unroll
      for (int reg = 0; reg < 4; ++reg)
        sh[(r*16 + quad*4 + reg)*260 + o] = fmaxf(acc[r][t][reg] + bv, 0.f);
    }
  __syncthreads();

  if (tid < 96) {
    const int pp = tid / 3, c = tid % 3;
    float s = h2b[c];
    for (int d = 0; d < 256; ++d) s += sh[pp*260 + d] * h2w[d*3 + c];
    if (c == 0) {
      const float hag = x[(size_t)(p0+pp)*4 + 3];
      s += scale[0] / (1.f + expf(-sharp[0]*(thresh[0] - hag)));
    }
    out[(size_t)(p0+pp)*3 + c] = s;
  }
}

// ---------------- launch ----------------
extern "C" void kernel_launch(void* const* d_in, const int* in_sizes, int n_in,
                              void* d_out, int out_size, void* d_ws, size_t ws_size,
                              hipStream_t stream) {
  const float* x       = (const float*)d_in[0];
  const float* hmix_a  = (const float*)d_in[1];
  const float* hmix_b  = (const float*)d_in[2];
  const float* hmix_c  = (const float*)d_in[3];
  const float* stem_w  = (const float*)d_in[4];
  const float* stem_b  = (const float*)d_in[5];
  const float* b1_w    = (const float*)d_in[6];
  const float* b1_b    = (const float*)d_in[7];
  const float* b2_w    = (const float*)d_in[8];
  const float* b2_b    = (const float*)d_in[9];
  const float* glob_w  = (const float*)d_in[10];
  const float* glob_b  = (const float*)d_in[11];
  const float* head1_w = (const float*)d_in[12];
  const float* head1_b = (const float*)d_in[13];
  const float* head2_w = (const float*)d_in[14];
  const float* head2_b = (const float*)d_in[15];
  const float* thresh  = (const float*)d_in[16];
  const float* sharp   = (const float*)d_in[17];
  const float* scale   = (const float*)d_in[18];
  float* out = (float*)d_out;

  char* base = (char*)d_ws;
  float*     coords4 = (float*)    (base + 0);          // 512 KB
  int*       idxb    = (int*)      (base + 524288);     // 2 MB
  _Float16*  fx0     = (_Float16*) (base + 2621440);    // 6 MB   (32768*96*2)
  _Float16*  fx1     = (_Float16*) (base + 8912896);    // 10 MB  (32768*160*2)
  _Float16*  f2h     = (_Float16*) (base + 19398656);   // 16 MB  (32768*256*2)
  // qa/cbq alias the f2h region: consumed by knn, f2h written only later (aggm2)
  _Float16*  qa      = (_Float16*) (base + 19398656);   // 1 MB   (32768*16*2)
  _Float16*  cbq     = (_Float16*) (base + 20447232);   // 1 MB
  _Float16*  w1m     = (_Float16*) (base + 36175872);   // 24 KB  (128*96*2)
  _Float16*  w1d     = (_Float16*) (base + 36200448);   // 24 KB
  _Float16*  w2m     = (_Float16*) (base + 36225024);   // 80 KB  (256*160*2)
  _Float16*  w2d     = (_Float16*) (base + 36306944);   // 80 KB
  _Float16*  h1wT    = (_Float16*) (base + 36388864);   // 256 KB (256*512*2)
  float*     part    = (float*)    (base + 36651008);   // 4 KB (4*256 f32, fused max)
  _Float16*  g2h     = (_Float16*) (base + 36782080);   // 2 KB
  const int NP = B_ * N_;   // 32768 points

  prep_kernel<<<NP/4 + W1_ + 2*W2_ + 1, 256, 0, stream>>>(
      x, stem_w, stem_b, hmix_a, hmix_b, hmix_c, coords4, fx0, fx1,
      b1_w, b2_w, head1_w, w1m, w1d, w2m, w2d, h1wT, qa, cbq, part);
  knn_kernel<<<NP/32, 512, 0, stream>>>(coords4, qa, cbq, idxb);
  aggm_kernel<3, 1, false><<<NP/16, 256, 0, stream>>>(
      fx0, idxb, w1m, w1d, b1_b, fx1, X1_, (u32*)0);
  aggm_kernel<5, 2, true><<<NP/16, 256, 0, stream>>>(
      fx1, idxb, w2m, w2d, b2_b, f2h, W2_, (u32*)part);
  gfc_kernel<<<B_, 256, 0, stream>>>(part, glob_w, glob_b, g2h);
  headm_kernel<<<NP/32, 256, 0, stream>>>(f2h, g2h, h1wT, head1_b, head2_w, head2_b,
                                          x, thresh, sharp, scale, out);
}